// Round 5
// baseline (4784.157 us; speedup 1.0000x reference)
//
#include <hip/hip_runtime.h>
#include <cstdint>
#include <cstddef>

#define Bq   4
#define Nq   8192
#define Cq   128
#define NPq  2048
#define KSEL 17

typedef float v2f __attribute__((ext_vector_type(2)));

// --- numerics helpers (rn ops / contract-off; must match numpy fp32 order) ---
__device__ __forceinline__ float rn_sq3(float x, float y, float z) {
  return __fadd_rn(__fadd_rn(__fmul_rn(x, x), __fmul_rn(y, y)), __fmul_rn(z, z));
}

// packed 2-point squared distance, exact rn per-op, order ((dx^2+dy^2)+dz^2)
__device__ __forceinline__ v2f dist2_v2(v2f px, v2f py, v2f pz, float cx, float cy, float cz) {
#pragma clang fp contract(off)
  v2f dx = px - cx;
  v2f dy = py - cy;
  v2f dz = pz - cz;
  v2f s = dx * dx + dy * dy + dz * dz;  // (mul,mul,mul,add,add), left-assoc
  return s;
}

// expanded-form squared distance, matching ref: max(sumq + sump - 2*dot, 0)
__device__ __forceinline__ float sq_expand(float qx, float qy, float qz, float sq_,
                                           float px, float py, float pz, float sp_) {
  float dot = __fadd_rn(__fadd_rn(__fmul_rn(qx, px), __fmul_rn(qy, py)), __fmul_rn(qz, pz));
  float v = __fsub_rn(__fadd_rn(sq_, sp_), __fmul_rn(2.0f, dot));
  v = fmaxf(v, 0.0f);
  return __fadd_rn(v, 0.0f);  // -0.0 -> +0.0 so float bits are monotonic as uint
}

// ---------------- K0: sum of squares per point (+ packed x,y,z,sump) ----------------
__global__ __launch_bounds__(256) void k_sump(const float* __restrict__ pts,
                                              float* __restrict__ sump,
                                              float4* __restrict__ pxyzs) {
  int g = blockIdx.x * 256 + threadIdx.x;  // over B*N
  float x = pts[g * 3 + 0], y = pts[g * 3 + 1], z = pts[g * 3 + 2];
  float s = rn_sq3(x, y, z);
  sump[g] = s;
  pxyzs[g] = make_float4(x, y, z, s);
}

// ---------------- K1: furthest point sampling (1 block / batch) ----------------
// 256 threads (4 waves = 1/SIMD), 32 CONTIGUOUS points/thread (p = tid*32+k) so
// (wave, lane, k) lexicographic order == original index order (exact jnp.argmax
// tie-breaks). Per iteration:
//   - value-only packed min/max update (issue floor ~384cy/SIMD, fixed)
//   - DPP wave f32-max; ballot picks lowest tied lane; ONLY that lane rescans
//     its 32 register dists (reverse scan -> lowest k) and posts a float4 slot
//     (val, cx, cy, cz) -- coords straight from its registers
//   - ONE barrier; all threads serially scan the 4 slots (strict > keeps the
//     lowest wave); centroid coords come directly from slot registers -- no
//     post-scan LDS/global loads at all
//   - fps_idx written by the global winner (exec-masked store, off crit path)
template <int CTRL, int RM, int BM>
__device__ __forceinline__ float dpp_maxf(float v) {
  int r = __builtin_amdgcn_update_dpp(__float_as_int(v), __float_as_int(v), CTRL, RM, BM, false);
  return fmaxf(v, __int_as_float(r));
}

__global__ __launch_bounds__(256) void k_fps(const float4* __restrict__ pxyzs,
                                             int* __restrict__ fps_idx) {
  const int b = blockIdx.x;
  const int tid = threadIdx.x;
  const int lane = tid & 63, wid = tid >> 6;
  const float4* PS = pxyzs + (size_t)b * Nq;

  __shared__ float4 slot[2][4];

  v2f px[16], py[16], pz[16], dd[16];
  const int pbase = tid * 32;

  float4 q0 = PS[0];
  v2f bdv;
  bdv.x = -1.0f; bdv.y = -1.0f;
#pragma unroll
  for (int j = 0; j < 16; j++) {
    float4 a = PS[pbase + 2 * j];
    float4 c = PS[pbase + 2 * j + 1];
    v2f tx, ty, tz;
    tx.x = a.x; tx.y = c.x;
    ty.x = a.y; ty.y = c.y;
    tz.x = a.z; tz.y = c.z;
    px[j] = tx; py[j] = ty; pz[j] = tz;
    v2f s = dist2_v2(tx, ty, tz, q0.x, q0.y, q0.z);
    dd[j] = s;
    bdv.x = fmaxf(bdv.x, s.x);
    bdv.y = fmaxf(bdv.y, s.y);
  }
  float bd = fmaxf(bdv.x, bdv.y);
  if (tid == 0) fps_idx[b * NPq] = 0;

  for (int i = 1; i < NPq; i++) {
    // wave max (value only) via DPP; full max lands in lane 63
    float wv = bd;
    wv = dpp_maxf<0x111, 0xf, 0xf>(wv);
    wv = dpp_maxf<0x112, 0xf, 0xf>(wv);
    wv = dpp_maxf<0x114, 0xf, 0xf>(wv);
    wv = dpp_maxf<0x118, 0xf, 0xf>(wv);
    wv = dpp_maxf<0x142, 0xa, 0xf>(wv);
    wv = dpp_maxf<0x143, 0xc, 0xf>(wv);
    float wmax = __int_as_float(__builtin_amdgcn_readlane(__float_as_int(wv), 63));
    unsigned long long msk = __ballot(bd == wmax);
    int wl = (int)__ffsll(msk) - 1;  // lowest tied lane = smallest index
    bool iamw = (lane == wl);
    int bip = 0;
    if (iamw) {
      int kk = 31;  // reverse scan -> smallest k on ties
#pragma unroll
      for (int j = 15; j >= 0; j--) {
        if (dd[j].y == wmax) kk = 2 * j + 1;
        if (dd[j].x == wmax) kk = 2 * j;
      }
      bip = pbase + kk;
      int jj = kk >> 1;
      bool odd = (kk & 1) != 0;
      float cx = odd ? px[jj].y : px[jj].x;
      float cy = odd ? py[jj].y : py[jj].x;
      float cz = odd ? pz[jj].y : pz[jj].x;
      slot[i & 1][wid] = make_float4(wmax, cx, cy, cz);
    }
    __syncthreads();

    // serial scan of the 4 wave slots; strict > keeps lowest wave on ties
    float4 s0 = slot[i & 1][0], s1 = slot[i & 1][1];
    float4 s2 = slot[i & 1][2], s3 = slot[i & 1][3];
    float bv = s0.x, cx = s0.y, cy = s0.z, cz = s0.w;
    int ws = 0;
    if (s1.x > bv) { bv = s1.x; cx = s1.y; cy = s1.z; cz = s1.w; ws = 1; }
    if (s2.x > bv) { bv = s2.x; cx = s2.y; cy = s2.z; cz = s2.w; ws = 2; }
    if (s3.x > bv) { bv = s3.x; cx = s3.y; cy = s3.z; cz = s3.w; ws = 3; }
    if (iamw && wid == ws) fps_idx[b * NPq + i] = bip;

    // value-only packed update
    bdv.x = -1.0f; bdv.y = -1.0f;
#pragma unroll
    for (int j = 0; j < 16; j++) {
      v2f s = dist2_v2(px[j], py[j], pz[j], cx, cy, cz);
      v2f nd;
      nd.x = fminf(dd[j].x, s.x);
      nd.y = fminf(dd[j].y, s.y);
      dd[j] = nd;
      bdv.x = fmaxf(bdv.x, nd.x);
      bdv.y = fmaxf(bdv.y, nd.y);
    }
    bd = fmaxf(bdv.x, bdv.y);
  }
}

// ---------------- K1b: gather sampled coords + sum-of-squares (+SoA copies) ----------------
__global__ __launch_bounds__(256) void k_gatherq(const float* __restrict__ pts,
                                                 const float* __restrict__ sump,
                                                 const int* __restrict__ fps_idx,
                                                 float* __restrict__ xyzq,
                                                 float* __restrict__ sumq,
                                                 float* __restrict__ xqs,
                                                 float* __restrict__ yqs,
                                                 float* __restrict__ zqs) {
  int g = blockIdx.x * 256 + threadIdx.x;  // over B*NP
  int b = g >> 11;
  int idx = fps_idx[g];
  int src = b * Nq + idx;
  float x = pts[src * 3 + 0], y = pts[src * 3 + 1], z = pts[src * 3 + 2];
  xyzq[g * 3 + 0] = x;
  xyzq[g * 3 + 1] = y;
  xyzq[g * 3 + 2] = z;
  xqs[g] = x; yqs[g] = y; zqs[g] = z;
  sumq[g] = sump[src];  // bitwise-identical to ref's sum(xyz_q**2)
}

// ---------------- K2: kNN top-17 per query + grouped mean-pool ----------------
// one block (256 thr) per query. Per-thread min key cached in a register; per
// round only the removed point's owner rescans its 32 entries. 1 barrier/round.
// Staging reads the packed (x,y,z,sump) float4 array: 1 dwordx4/point.
__global__ __launch_bounds__(256) void k_knn_group(const float4* __restrict__ pxyzs,
                                                   const float* __restrict__ xyzq,
                                                   const float* __restrict__ sumq,
                                                   const float* __restrict__ feats,
                                                   float* __restrict__ coarse_t) {
  const int blk = blockIdx.x;  // over B*NP
  const int b = blk >> 11;
  const int tid = threadIdx.x;
  const int lane = tid & 63, wid = tid >> 6;
  const float4* PS = pxyzs + (size_t)b * Nq;

  __shared__ float sq_lds[Nq];
  __shared__ unsigned long long wk[2][4];
  __shared__ int sel[KSEL];

  float qx = xyzq[blk * 3 + 0], qy = xyzq[blk * 3 + 1], qz = xyzq[blk * 3 + 2];
  float sq_ = sumq[blk];

  unsigned long long lmin = ~0ull;
#pragma unroll
  for (int k = 0; k < 32; k++) {
    int p = k * 256 + tid;
    float4 t = PS[p];
    float v = sq_expand(qx, qy, qz, sq_, t.x, t.y, t.z, t.w);
    sq_lds[p] = v;
    unsigned long long key = ((unsigned long long)__float_as_uint(v) << 32) | (unsigned int)p;
    lmin = key < lmin ? key : lmin;
  }
  // no barrier: each thread only ever touches its own sq_lds entries (p%256==tid)

  for (int r = 0; r < KSEL; r++) {
    unsigned long long key = lmin;
#pragma unroll
    for (int off = 32; off > 0; off >>= 1) {
      unsigned long long o = __shfl_down(key, off);
      key = o < key ? o : key;
    }
    if (lane == 0) wk[r & 1][wid] = key;
    __syncthreads();
    unsigned long long m = wk[r & 1][0];
    m = wk[r & 1][1] < m ? wk[r & 1][1] : m;
    m = wk[r & 1][2] < m ? wk[r & 1][2] : m;
    m = wk[r & 1][3] < m ? wk[r & 1][3] : m;
    int p = (int)(unsigned int)(m & 0xFFFFFFFFull);
    if (tid == 0) sel[r] = p;
    if ((p & 255) == tid) {  // owner removes winner and rebuilds its local min
      sq_lds[p] = __uint_as_float(0x7f800000u);
      lmin = ~0ull;
#pragma unroll
      for (int k = 0; k < 32; k++) {
        int pp = k * 256 + tid;
        unsigned long long kk =
            ((unsigned long long)__float_as_uint(sq_lds[pp]) << 32) | (unsigned int)pp;
        lmin = kk < lmin ? kk : lmin;
      }
    }
  }
  __syncthreads();

  // grouped mean over neighbors sel[1..16] (self at sel[0] dropped)
  if (tid < Cq) {
    const float* F = feats + ((size_t)(b * Cq + tid)) * Nq;
    float acc = 0.0f;
#pragma unroll
    for (int j = 1; j < KSEL; j++) acc += F[sel[j]];
    coarse_t[(size_t)blk * Cq + tid] = acc * (1.0f / 16.0f);
  }
}

// ---------------- K3: three_nn (top-3 queries per point) + weights ----------------
__device__ __forceinline__ void merge3(unsigned long long& a0, unsigned long long& a1,
                                       unsigned long long& a2, unsigned long long b0,
                                       unsigned long long b1, unsigned long long b2) {
  unsigned long long lo1 = a0 < b0 ? a0 : b0;
  unsigned long long hi1 = a0 < b0 ? b0 : a0;
  unsigned long long lo2 = a1 < b1 ? a1 : b1;
  unsigned long long hi2 = a1 < b1 ? b1 : a1;
  unsigned long long lo3 = a2 < b2 ? a2 : b2;
  unsigned long long c1 = hi1 < lo2 ? hi1 : lo2;
  unsigned long long m1 = hi1 < lo2 ? lo2 : hi1;
  unsigned long long m2 = hi2 < lo3 ? hi2 : lo3;
  a0 = lo1;
  a1 = c1;
  a2 = m1 < m2 ? m1 : m2;
}

__global__ __launch_bounds__(256) void k_three(const float* __restrict__ pts,
                                               const float* __restrict__ sump,
                                               const float* __restrict__ xqs,
                                               const float* __restrict__ yqs,
                                               const float* __restrict__ zqs,
                                               const float* __restrict__ sumq,
                                               int* __restrict__ i0, int* __restrict__ i1,
                                               int* __restrict__ i2, float* __restrict__ w0,
                                               float* __restrict__ w1, float* __restrict__ w2) {
  const int wid = threadIdx.x >> 6, lane = threadIdx.x & 63;
  const int n = blockIdx.x * 4 + wid;  // global over B*N
  const int b = n >> 13;
  float px = pts[n * 3 + 0], py = pts[n * 3 + 1], pz = pts[n * 3 + 2];
  float sp = sump[n];
  const float* QX = xqs + (size_t)b * NPq;
  const float* QY = yqs + (size_t)b * NPq;
  const float* QZ = zqs + (size_t)b * NPq;
  const float* SQ = sumq + (size_t)b * NPq;

  unsigned long long k0 = ~0ull, k1 = ~0ull, k2 = ~0ull;
#pragma unroll 4
  for (int j = 0; j < 32; j++) {
    int q = lane + j * 64;
    float v = sq_expand(QX[q], QY[q], QZ[q], SQ[q], px, py, pz, sp);
    unsigned long long key = ((unsigned long long)__float_as_uint(v) << 32) | (unsigned int)q;
    if (key < k2) {
      if (key < k1) {
        k2 = k1;
        if (key < k0) { k1 = k0; k0 = key; } else { k1 = key; }
      } else {
        k2 = key;
      }
    }
  }
#pragma unroll
  for (int off = 32; off > 0; off >>= 1) {
    unsigned long long o0 = __shfl_down(k0, off);
    unsigned long long o1 = __shfl_down(k1, off);
    unsigned long long o2 = __shfl_down(k2, off);
    merge3(k0, k1, k2, o0, o1, o2);
  }
  if (lane == 0) {
    float v0 = __uint_as_float((unsigned int)(k0 >> 32));
    float v1 = __uint_as_float((unsigned int)(k1 >> 32));
    float v2 = __uint_as_float((unsigned int)(k2 >> 32));
    float d0 = fmaxf(v0, 1e-10f), d1 = fmaxf(v1, 1e-10f), d2 = fmaxf(v2, 1e-10f);
    float inv0 = 1.0f / (d0 + 1e-8f);
    float inv1 = 1.0f / (d1 + 1e-8f);
    float inv2 = 1.0f / (d2 + 1e-8f);
    float s = inv0 + inv1 + inv2;
    i0[n] = (int)(unsigned int)(k0 & 0xFFFFFFFFull);
    i1[n] = (int)(unsigned int)(k1 & 0xFFFFFFFFull);
    i2[n] = (int)(unsigned int)(k2 & 0xFFFFFFFFull);
    w0[n] = inv0 / s;
    w1[n] = inv1 / s;
    w2[n] = inv2 / s;
  }
}

// ---------------- K4: inverse-distance interpolation ----------------
__global__ __launch_bounds__(256) void k_interp(const float* __restrict__ coarse_t,
                                                const int* __restrict__ i0,
                                                const int* __restrict__ i1,
                                                const int* __restrict__ i2,
                                                const float* __restrict__ w0,
                                                const float* __restrict__ w1,
                                                const float* __restrict__ w2,
                                                float* __restrict__ out) {
  int g = blockIdx.x * 256 + threadIdx.x;  // over B*N
  int b = g >> 13, n = g & (Nq - 1);
  int a0 = i0[g], a1 = i1[g], a2 = i2[g];
  float u0 = w0[g], u1 = w1[g], u2 = w2[g];
  const float4* r0 = (const float4*)(coarse_t + ((size_t)b * NPq + a0) * Cq);
  const float4* r1 = (const float4*)(coarse_t + ((size_t)b * NPq + a1) * Cq);
  const float4* r2 = (const float4*)(coarse_t + ((size_t)b * NPq + a2) * Cq);
  float* O = out + (size_t)b * Cq * Nq + n;
#pragma unroll 4
  for (int cq = 0; cq < Cq / 4; cq++) {
    float4 f0 = r0[cq], f1 = r1[cq], f2 = r2[cq];
    float o0 = u0 * f0.x + u1 * f1.x + u2 * f2.x;
    float o1 = u0 * f0.y + u1 * f1.y + u2 * f2.y;
    float o2 = u0 * f0.z + u1 * f1.z + u2 * f2.z;
    float o3 = u0 * f0.w + u1 * f1.w + u2 * f2.w;
    O[(size_t)(cq * 4 + 0) * Nq] = o0;
    O[(size_t)(cq * 4 + 1) * Nq] = o1;
    O[(size_t)(cq * 4 + 2) * Nq] = o2;
    O[(size_t)(cq * 4 + 3) * Nq] = o3;
  }
}

// ---------------- launch ----------------
extern "C" void kernel_launch(void* const* d_in, const int* in_sizes, int n_in,
                              void* d_out, int out_size, void* d_ws, size_t ws_size,
                              hipStream_t stream) {
  const float* pts = (const float*)d_in[0];    // [B,N,3]
  const float* feats = (const float*)d_in[1];  // [B,C,N]
  float* out = (float*)d_out;                  // [B,C,N]

  char* ws = (char*)d_ws;
  size_t off = 0;
  auto alloc = [&](size_t bytes) {
    void* p = ws + off;
    off += (bytes + 255) & ~(size_t)255;
    return p;
  };
  float* sump = (float*)alloc((size_t)Bq * Nq * 4);
  float4* pxyzs = (float4*)alloc((size_t)Bq * Nq * 16);
  int* fps_idx = (int*)alloc((size_t)Bq * NPq * 4);
  float* xyzq = (float*)alloc((size_t)Bq * NPq * 3 * 4);
  float* sumq = (float*)alloc((size_t)Bq * NPq * 4);
  float* coarse_t = (float*)alloc((size_t)Bq * NPq * Cq * 4);
  int* i0 = (int*)alloc((size_t)Bq * Nq * 4);
  int* i1 = (int*)alloc((size_t)Bq * Nq * 4);
  int* i2 = (int*)alloc((size_t)Bq * Nq * 4);
  float* w0 = (float*)alloc((size_t)Bq * Nq * 4);
  float* w1 = (float*)alloc((size_t)Bq * Nq * 4);
  float* w2 = (float*)alloc((size_t)Bq * Nq * 4);
  float* xqs = (float*)alloc((size_t)Bq * NPq * 4);
  float* yqs = (float*)alloc((size_t)Bq * NPq * 4);
  float* zqs = (float*)alloc((size_t)Bq * NPq * 4);

  k_sump<<<(Bq * Nq) / 256, 256, 0, stream>>>(pts, sump, pxyzs);
  k_fps<<<Bq, 256, 0, stream>>>(pxyzs, fps_idx);
  k_gatherq<<<(Bq * NPq) / 256, 256, 0, stream>>>(pts, sump, fps_idx, xyzq, sumq, xqs, yqs, zqs);
  k_knn_group<<<Bq * NPq, 256, 0, stream>>>(pxyzs, xyzq, sumq, feats, coarse_t);
  k_three<<<(Bq * Nq) / 4, 256, 0, stream>>>(pts, sump, xqs, yqs, zqs, sumq, i0, i1, i2, w0, w1, w2);
  k_interp<<<(Bq * Nq) / 256, 256, 0, stream>>>(coarse_t, i0, i1, i2, w0, w1, w2, out);
}

// Round 6
// 3718.234 us; speedup vs baseline: 1.2867x; 1.2867x over previous
//
#include <hip/hip_runtime.h>
#include <cstdint>
#include <cstddef>

#define Bq   4
#define Nq   8192
#define Cq   128
#define NPq  2048
#define KSEL 17

typedef float v2f __attribute__((ext_vector_type(2)));

// --- numerics helpers (rn ops / contract-off; must match numpy fp32 order) ---
__device__ __forceinline__ float rn_sq3(float x, float y, float z) {
  return __fadd_rn(__fadd_rn(__fmul_rn(x, x), __fmul_rn(y, y)), __fmul_rn(z, z));
}

// packed 2-point squared distance, exact rn per-op, order ((dx^2+dy^2)+dz^2)
__device__ __forceinline__ v2f dist2_v2(v2f px, v2f py, v2f pz, float cx, float cy, float cz) {
#pragma clang fp contract(off)
  v2f dx = px - cx;
  v2f dy = py - cy;
  v2f dz = pz - cz;
  v2f s = dx * dx + dy * dy + dz * dz;  // (mul,mul,mul,add,add), left-assoc
  return s;
}

// expanded-form squared distance, matching ref: max(sumq + sump - 2*dot, 0)
__device__ __forceinline__ float sq_expand(float qx, float qy, float qz, float sq_,
                                           float px, float py, float pz, float sp_) {
  float dot = __fadd_rn(__fadd_rn(__fmul_rn(qx, px), __fmul_rn(qy, py)), __fmul_rn(qz, pz));
  float v = __fsub_rn(__fadd_rn(sq_, sp_), __fmul_rn(2.0f, dot));
  v = fmaxf(v, 0.0f);
  return __fadd_rn(v, 0.0f);  // -0.0 -> +0.0 so float bits are monotonic as uint
}

// ---------------- K0: sum of squares per point (+ packed x,y,z,sump) ----------------
__global__ __launch_bounds__(256) void k_sump(const float* __restrict__ pts,
                                              float* __restrict__ sump,
                                              float4* __restrict__ pxyzs) {
  int g = blockIdx.x * 256 + threadIdx.x;  // over B*N
  float x = pts[g * 3 + 0], y = pts[g * 3 + 1], z = pts[g * 3 + 2];
  float s = rn_sq3(x, y, z);
  sump[g] = s;
  pxyzs[g] = make_float4(x, y, z, s);
}

// ---------------- K1: furthest point sampling (1 block / batch) ----------------
// 512 threads (8 waves = 2/SIMD for latency hiding), 16 CONTIGUOUS points per
// thread (p = tid*16+k) so (wave, lane, k) lexicographic order == original
// index order (exact jnp.argmax tie-breaks). Per iteration:
//   - value-only packed min/max update
//   - DPP wave f32-max; ballot picks lowest tied lane; ONLY that lane rescans
//     its 16 register dists (reverse scan -> lowest k) and posts a float4 slot
//     (val, cx, cy, cz) -- coords straight from its registers
//   - ONE barrier; all threads serially scan the 8 slots (strict > keeps the
//     lowest wave); centroid comes directly from slot registers -- NO
//     post-scan LDS/global dependent fetch
//   - fps_idx written by the global winner lane (off critical path)
// __launch_bounds__(512,2): min 2 waves/EU -> VGPR cap 256, keeps the
// px/py/pz/dd arrays in true VGPRs (R3 showed AGPR spill at tighter caps).
template <int CTRL, int RM, int BM>
__device__ __forceinline__ float dpp_maxf(float v) {
  int r = __builtin_amdgcn_update_dpp(__float_as_int(v), __float_as_int(v), CTRL, RM, BM, false);
  return fmaxf(v, __int_as_float(r));
}

__global__ __launch_bounds__(512, 2) void k_fps(const float4* __restrict__ pxyzs,
                                                int* __restrict__ fps_idx) {
  const int b = blockIdx.x;
  const int tid = threadIdx.x;
  const int lane = tid & 63, wid = tid >> 6;
  const float4* PS = pxyzs + (size_t)b * Nq;

  __shared__ float4 slot[2][8];

  v2f px[8], py[8], pz[8], dd[8];
  const int pbase = tid * 16;

  float4 q0 = PS[0];
  v2f bdv;
  bdv.x = -1.0f; bdv.y = -1.0f;
#pragma unroll
  for (int j = 0; j < 8; j++) {
    float4 a = PS[pbase + 2 * j];
    float4 c = PS[pbase + 2 * j + 1];
    v2f tx, ty, tz;
    tx.x = a.x; tx.y = c.x;
    ty.x = a.y; ty.y = c.y;
    tz.x = a.z; tz.y = c.z;
    px[j] = tx; py[j] = ty; pz[j] = tz;
    v2f s = dist2_v2(tx, ty, tz, q0.x, q0.y, q0.z);
    dd[j] = s;
    bdv.x = fmaxf(bdv.x, s.x);
    bdv.y = fmaxf(bdv.y, s.y);
  }
  float bd = fmaxf(bdv.x, bdv.y);
  if (tid == 0) fps_idx[b * NPq] = 0;

  for (int i = 1; i < NPq; i++) {
    // wave max (value only) via DPP; full max lands in lane 63
    float wv = bd;
    wv = dpp_maxf<0x111, 0xf, 0xf>(wv);
    wv = dpp_maxf<0x112, 0xf, 0xf>(wv);
    wv = dpp_maxf<0x114, 0xf, 0xf>(wv);
    wv = dpp_maxf<0x118, 0xf, 0xf>(wv);
    wv = dpp_maxf<0x142, 0xa, 0xf>(wv);
    wv = dpp_maxf<0x143, 0xc, 0xf>(wv);
    float wmax = __int_as_float(__builtin_amdgcn_readlane(__float_as_int(wv), 63));
    unsigned long long msk = __ballot(bd == wmax);
    int wl = (int)__ffsll(msk) - 1;  // lowest tied lane = smallest index
    bool iamw = (lane == wl);
    int bip = 0;
    if (iamw) {
      int kk = 15;  // reverse scan -> smallest k on ties
#pragma unroll
      for (int j = 7; j >= 0; j--) {
        if (dd[j].y == wmax) kk = 2 * j + 1;
        if (dd[j].x == wmax) kk = 2 * j;
      }
      bip = pbase + kk;
      int jj = kk >> 1;
      bool odd = (kk & 1) != 0;
      float wx = odd ? px[jj].y : px[jj].x;
      float wy = odd ? py[jj].y : py[jj].x;
      float wz = odd ? pz[jj].y : pz[jj].x;
      slot[i & 1][wid] = make_float4(wmax, wx, wy, wz);
    }
    __syncthreads();

    // serial scan of the 8 wave slots; strict > keeps lowest wave on ties
    float4 s0 = slot[i & 1][0];
    float bv = s0.x, cx = s0.y, cy = s0.z, cz = s0.w;
    int ws = 0;
#pragma unroll
    for (int w = 1; w < 8; w++) {
      float4 sw = slot[i & 1][w];
      bool t = sw.x > bv;
      bv = t ? sw.x : bv;
      cx = t ? sw.y : cx;
      cy = t ? sw.z : cy;
      cz = t ? sw.w : cz;
      ws = t ? w : ws;
    }
    if (iamw && wid == ws) fps_idx[b * NPq + i] = bip;

    // value-only packed update
    bdv.x = -1.0f; bdv.y = -1.0f;
#pragma unroll
    for (int j = 0; j < 8; j++) {
      v2f s = dist2_v2(px[j], py[j], pz[j], cx, cy, cz);
      v2f nd;
      nd.x = fminf(dd[j].x, s.x);
      nd.y = fminf(dd[j].y, s.y);
      dd[j] = nd;
      bdv.x = fmaxf(bdv.x, nd.x);
      bdv.y = fmaxf(bdv.y, nd.y);
    }
    bd = fmaxf(bdv.x, bdv.y);
  }
}

// ---------------- K1b: gather sampled coords + sum-of-squares (+SoA copies) ----------------
__global__ __launch_bounds__(256) void k_gatherq(const float* __restrict__ pts,
                                                 const float* __restrict__ sump,
                                                 const int* __restrict__ fps_idx,
                                                 float* __restrict__ xyzq,
                                                 float* __restrict__ sumq,
                                                 float* __restrict__ xqs,
                                                 float* __restrict__ yqs,
                                                 float* __restrict__ zqs) {
  int g = blockIdx.x * 256 + threadIdx.x;  // over B*NP
  int b = g >> 11;
  int idx = fps_idx[g];
  int src = b * Nq + idx;
  float x = pts[src * 3 + 0], y = pts[src * 3 + 1], z = pts[src * 3 + 2];
  xyzq[g * 3 + 0] = x;
  xyzq[g * 3 + 1] = y;
  xyzq[g * 3 + 2] = z;
  xqs[g] = x; yqs[g] = y; zqs[g] = z;
  sumq[g] = sump[src];  // bitwise-identical to ref's sum(xyz_q**2)
}

// ---------------- K2: kNN top-17 per query + grouped mean-pool ----------------
// one block (256 thr) per query. Per-thread min key cached in a register; per
// round only the removed point's owner rescans its 32 entries. 1 barrier/round.
// Staging reads the packed (x,y,z,sump) float4 array: 1 dwordx4/point.
__global__ __launch_bounds__(256) void k_knn_group(const float4* __restrict__ pxyzs,
                                                   const float* __restrict__ xyzq,
                                                   const float* __restrict__ sumq,
                                                   const float* __restrict__ feats,
                                                   float* __restrict__ coarse_t) {
  const int blk = blockIdx.x;  // over B*NP
  const int b = blk >> 11;
  const int tid = threadIdx.x;
  const int lane = tid & 63, wid = tid >> 6;
  const float4* PS = pxyzs + (size_t)b * Nq;

  __shared__ float sq_lds[Nq];
  __shared__ unsigned long long wk[2][4];
  __shared__ int sel[KSEL];

  float qx = xyzq[blk * 3 + 0], qy = xyzq[blk * 3 + 1], qz = xyzq[blk * 3 + 2];
  float sq_ = sumq[blk];

  unsigned long long lmin = ~0ull;
#pragma unroll
  for (int k = 0; k < 32; k++) {
    int p = k * 256 + tid;
    float4 t = PS[p];
    float v = sq_expand(qx, qy, qz, sq_, t.x, t.y, t.z, t.w);
    sq_lds[p] = v;
    unsigned long long key = ((unsigned long long)__float_as_uint(v) << 32) | (unsigned int)p;
    lmin = key < lmin ? key : lmin;
  }
  // no barrier: each thread only ever touches its own sq_lds entries (p%256==tid)

  for (int r = 0; r < KSEL; r++) {
    unsigned long long key = lmin;
#pragma unroll
    for (int off = 32; off > 0; off >>= 1) {
      unsigned long long o = __shfl_down(key, off);
      key = o < key ? o : key;
    }
    if (lane == 0) wk[r & 1][wid] = key;
    __syncthreads();
    unsigned long long m = wk[r & 1][0];
    m = wk[r & 1][1] < m ? wk[r & 1][1] : m;
    m = wk[r & 1][2] < m ? wk[r & 1][2] : m;
    m = wk[r & 1][3] < m ? wk[r & 1][3] : m;
    int p = (int)(unsigned int)(m & 0xFFFFFFFFull);
    if (tid == 0) sel[r] = p;
    if ((p & 255) == tid) {  // owner removes winner and rebuilds its local min
      sq_lds[p] = __uint_as_float(0x7f800000u);
      lmin = ~0ull;
#pragma unroll
      for (int k = 0; k < 32; k++) {
        int pp = k * 256 + tid;
        unsigned long long kk =
            ((unsigned long long)__float_as_uint(sq_lds[pp]) << 32) | (unsigned int)pp;
        lmin = kk < lmin ? kk : lmin;
      }
    }
  }
  __syncthreads();

  // grouped mean over neighbors sel[1..16] (self at sel[0] dropped)
  if (tid < Cq) {
    const float* F = feats + ((size_t)(b * Cq + tid)) * Nq;
    float acc = 0.0f;
#pragma unroll
    for (int j = 1; j < KSEL; j++) acc += F[sel[j]];
    coarse_t[(size_t)blk * Cq + tid] = acc * (1.0f / 16.0f);
  }
}

// ---------------- K3: three_nn (top-3 queries per point) + weights ----------------
__device__ __forceinline__ void merge3(unsigned long long& a0, unsigned long long& a1,
                                       unsigned long long& a2, unsigned long long b0,
                                       unsigned long long b1, unsigned long long b2) {
  unsigned long long lo1 = a0 < b0 ? a0 : b0;
  unsigned long long hi1 = a0 < b0 ? b0 : a0;
  unsigned long long lo2 = a1 < b1 ? a1 : b1;
  unsigned long long hi2 = a1 < b1 ? b1 : a1;
  unsigned long long lo3 = a2 < b2 ? a2 : b2;
  unsigned long long c1 = hi1 < lo2 ? hi1 : lo2;
  unsigned long long m1 = hi1 < lo2 ? lo2 : hi1;
  unsigned long long m2 = hi2 < lo3 ? hi2 : lo3;
  a0 = lo1;
  a1 = c1;
  a2 = m1 < m2 ? m1 : m2;
}

__global__ __launch_bounds__(256) void k_three(const float* __restrict__ pts,
                                               const float* __restrict__ sump,
                                               const float* __restrict__ xqs,
                                               const float* __restrict__ yqs,
                                               const float* __restrict__ zqs,
                                               const float* __restrict__ sumq,
                                               int* __restrict__ i0, int* __restrict__ i1,
                                               int* __restrict__ i2, float* __restrict__ w0,
                                               float* __restrict__ w1, float* __restrict__ w2) {
  const int wid = threadIdx.x >> 6, lane = threadIdx.x & 63;
  const int n = blockIdx.x * 4 + wid;  // global over B*N
  const int b = n >> 13;
  float px = pts[n * 3 + 0], py = pts[n * 3 + 1], pz = pts[n * 3 + 2];
  float sp = sump[n];
  const float* QX = xqs + (size_t)b * NPq;
  const float* QY = yqs + (size_t)b * NPq;
  const float* QZ = zqs + (size_t)b * NPq;
  const float* SQ = sumq + (size_t)b * NPq;

  unsigned long long k0 = ~0ull, k1 = ~0ull, k2 = ~0ull;
#pragma unroll 4
  for (int j = 0; j < 32; j++) {
    int q = lane + j * 64;
    float v = sq_expand(QX[q], QY[q], QZ[q], SQ[q], px, py, pz, sp);
    unsigned long long key = ((unsigned long long)__float_as_uint(v) << 32) | (unsigned int)q;
    if (key < k2) {
      if (key < k1) {
        k2 = k1;
        if (key < k0) { k1 = k0; k0 = key; } else { k1 = key; }
      } else {
        k2 = key;
      }
    }
  }
#pragma unroll
  for (int off = 32; off > 0; off >>= 1) {
    unsigned long long o0 = __shfl_down(k0, off);
    unsigned long long o1 = __shfl_down(k1, off);
    unsigned long long o2 = __shfl_down(k2, off);
    merge3(k0, k1, k2, o0, o1, o2);
  }
  if (lane == 0) {
    float v0 = __uint_as_float((unsigned int)(k0 >> 32));
    float v1 = __uint_as_float((unsigned int)(k1 >> 32));
    float v2 = __uint_as_float((unsigned int)(k2 >> 32));
    float d0 = fmaxf(v0, 1e-10f), d1 = fmaxf(v1, 1e-10f), d2 = fmaxf(v2, 1e-10f);
    float inv0 = 1.0f / (d0 + 1e-8f);
    float inv1 = 1.0f / (d1 + 1e-8f);
    float inv2 = 1.0f / (d2 + 1e-8f);
    float s = inv0 + inv1 + inv2;
    i0[n] = (int)(unsigned int)(k0 & 0xFFFFFFFFull);
    i1[n] = (int)(unsigned int)(k1 & 0xFFFFFFFFull);
    i2[n] = (int)(unsigned int)(k2 & 0xFFFFFFFFull);
    w0[n] = inv0 / s;
    w1[n] = inv1 / s;
    w2[n] = inv2 / s;
  }
}

// ---------------- K4: inverse-distance interpolation ----------------
__global__ __launch_bounds__(256) void k_interp(const float* __restrict__ coarse_t,
                                                const int* __restrict__ i0,
                                                const int* __restrict__ i1,
                                                const int* __restrict__ i2,
                                                const float* __restrict__ w0,
                                                const float* __restrict__ w1,
                                                const float* __restrict__ w2,
                                                float* __restrict__ out) {
  int g = blockIdx.x * 256 + threadIdx.x;  // over B*N
  int b = g >> 13, n = g & (Nq - 1);
  int a0 = i0[g], a1 = i1[g], a2 = i2[g];
  float u0 = w0[g], u1 = w1[g], u2 = w2[g];
  const float4* r0 = (const float4*)(coarse_t + ((size_t)b * NPq + a0) * Cq);
  const float4* r1 = (const float4*)(coarse_t + ((size_t)b * NPq + a1) * Cq);
  const float4* r2 = (const float4*)(coarse_t + ((size_t)b * NPq + a2) * Cq);
  float* O = out + (size_t)b * Cq * Nq + n;
#pragma unroll 4
  for (int cq = 0; cq < Cq / 4; cq++) {
    float4 f0 = r0[cq], f1 = r1[cq], f2 = r2[cq];
    float o0 = u0 * f0.x + u1 * f1.x + u2 * f2.x;
    float o1 = u0 * f0.y + u1 * f1.y + u2 * f2.y;
    float o2 = u0 * f0.z + u1 * f1.z + u2 * f2.z;
    float o3 = u0 * f0.w + u1 * f1.w + u2 * f2.w;
    O[(size_t)(cq * 4 + 0) * Nq] = o0;
    O[(size_t)(cq * 4 + 1) * Nq] = o1;
    O[(size_t)(cq * 4 + 2) * Nq] = o2;
    O[(size_t)(cq * 4 + 3) * Nq] = o3;
  }
}

// ---------------- launch ----------------
extern "C" void kernel_launch(void* const* d_in, const int* in_sizes, int n_in,
                              void* d_out, int out_size, void* d_ws, size_t ws_size,
                              hipStream_t stream) {
  const float* pts = (const float*)d_in[0];    // [B,N,3]
  const float* feats = (const float*)d_in[1];  // [B,C,N]
  float* out = (float*)d_out;                  // [B,C,N]

  char* ws = (char*)d_ws;
  size_t off = 0;
  auto alloc = [&](size_t bytes) {
    void* p = ws + off;
    off += (bytes + 255) & ~(size_t)255;
    return p;
  };
  float* sump = (float*)alloc((size_t)Bq * Nq * 4);
  float4* pxyzs = (float4*)alloc((size_t)Bq * Nq * 16);
  int* fps_idx = (int*)alloc((size_t)Bq * NPq * 4);
  float* xyzq = (float*)alloc((size_t)Bq * NPq * 3 * 4);
  float* sumq = (float*)alloc((size_t)Bq * NPq * 4);
  float* coarse_t = (float*)alloc((size_t)Bq * NPq * Cq * 4);
  int* i0 = (int*)alloc((size_t)Bq * Nq * 4);
  int* i1 = (int*)alloc((size_t)Bq * Nq * 4);
  int* i2 = (int*)alloc((size_t)Bq * Nq * 4);
  float* w0 = (float*)alloc((size_t)Bq * Nq * 4);
  float* w1 = (float*)alloc((size_t)Bq * Nq * 4);
  float* w2 = (float*)alloc((size_t)Bq * Nq * 4);
  float* xqs = (float*)alloc((size_t)Bq * NPq * 4);
  float* yqs = (float*)alloc((size_t)Bq * NPq * 4);
  float* zqs = (float*)alloc((size_t)Bq * NPq * 4);

  k_sump<<<(Bq * Nq) / 256, 256, 0, stream>>>(pts, sump, pxyzs);
  k_fps<<<Bq, 512, 0, stream>>>(pxyzs, fps_idx);
  k_gatherq<<<(Bq * NPq) / 256, 256, 0, stream>>>(pts, sump, fps_idx, xyzq, sumq, xqs, yqs, zqs);
  k_knn_group<<<Bq * NPq, 256, 0, stream>>>(pxyzs, xyzq, sumq, feats, coarse_t);
  k_three<<<(Bq * Nq) / 4, 256, 0, stream>>>(pts, sump, xqs, yqs, zqs, sumq, i0, i1, i2, w0, w1, w2);
  k_interp<<<(Bq * Nq) / 256, 256, 0, stream>>>(coarse_t, i0, i1, i2, w0, w1, w2, out);
}

// Round 7
// 2393.634 us; speedup vs baseline: 1.9987x; 1.5534x over previous
//
#include <hip/hip_runtime.h>
#include <cstdint>
#include <cstddef>

#define Bq   4
#define Nq   8192
#define Cq   128
#define NPq  2048
#define KSEL 17

typedef float v2f __attribute__((ext_vector_type(2)));

// --- numerics helpers (rn ops / contract-off; must match numpy fp32 order) ---
__device__ __forceinline__ float rn_sq3(float x, float y, float z) {
  return __fadd_rn(__fadd_rn(__fmul_rn(x, x), __fmul_rn(y, y)), __fmul_rn(z, z));
}

// packed 2-point squared distance, exact rn per-op, order ((dx^2+dy^2)+dz^2)
__device__ __forceinline__ v2f dist2_v2(v2f px, v2f py, v2f pz, float cx, float cy, float cz) {
#pragma clang fp contract(off)
  v2f dx = px - cx;
  v2f dy = py - cy;
  v2f dz = pz - cz;
  v2f s = dx * dx + dy * dy + dz * dz;  // (mul,mul,mul,add,add), left-assoc
  return s;
}

// expanded-form squared distance, matching ref: max(sumq + sump - 2*dot, 0)
__device__ __forceinline__ float sq_expand(float qx, float qy, float qz, float sq_,
                                           float px, float py, float pz, float sp_) {
  float dot = __fadd_rn(__fadd_rn(__fmul_rn(qx, px), __fmul_rn(qy, py)), __fmul_rn(qz, pz));
  float v = __fsub_rn(__fadd_rn(sq_, sp_), __fmul_rn(2.0f, dot));
  v = fmaxf(v, 0.0f);
  return __fadd_rn(v, 0.0f);  // -0.0 -> +0.0 so float bits are monotonic as uint
}

// ---------------- K0: sum of squares per point (+ packed x,y,z,sump) ----------------
__global__ __launch_bounds__(256) void k_sump(const float* __restrict__ pts,
                                              float* __restrict__ sump,
                                              float4* __restrict__ pxyzs) {
  int g = blockIdx.x * 256 + threadIdx.x;  // over B*N
  float x = pts[g * 3 + 0], y = pts[g * 3 + 1], z = pts[g * 3 + 2];
  float s = rn_sq3(x, y, z);
  sump[g] = s;
  pxyzs[g] = make_float4(x, y, z, s);
}

// ---------------- K1: furthest point sampling (1 block / batch) ----------------
// EXACT R3 structure (best measured: 2050us) with ONE change: winner indices
// accumulate in LDS (idx_lds) and are dumped to global once after the loop.
// This removes the per-iteration global store, whose L2 write-ack every wave
// had to drain (compiler's s_waitcnt vmcnt(0) before s_barrier) each round.
template <int CTRL, int RM, int BM>
__device__ __forceinline__ float dpp_maxf(float v) {
  int r = __builtin_amdgcn_update_dpp(__float_as_int(v), __float_as_int(v), CTRL, RM, BM, false);
  return fmaxf(v, __int_as_float(r));
}

__global__ __launch_bounds__(512) void k_fps(const float* __restrict__ pts,
                                             int* __restrict__ fps_idx) {
  const int b = blockIdx.x;
  const int tid = threadIdx.x;
  const int lane = tid & 63, wid = tid >> 6;
  const float* P = pts + (size_t)b * Nq * 3;

  __shared__ float sv[2][8];
  __shared__ int spi[2][8];
  __shared__ int idx_lds[NPq];

  v2f px[8], py[8], pz[8], dd[8];
  const int pbase = tid * 16;
#pragma unroll
  for (int j = 0; j < 8; j++) {
    const float2* q2 = (const float2*)(P + (size_t)(pbase + 2 * j) * 3);
    float2 A = q2[0], Bv = q2[1], Cv = q2[2];  // (x0,y0) (z0,x1) (y1,z1)
    v2f tx, ty, tz;
    tx.x = A.x;  tx.y = Bv.y;
    ty.x = A.y;  ty.y = Cv.x;
    tz.x = Bv.x; tz.y = Cv.y;
    px[j] = tx; py[j] = ty; pz[j] = tz;
  }
  float qx = P[0], qy = P[1], qz = P[2];
  float bd = -1.0f;
  int bp = pbase;
#pragma unroll
  for (int j = 0; j < 8; j++) {
    v2f s = dist2_v2(px[j], py[j], pz[j], qx, qy, qz);
    dd[j] = s;
    if (s.x > bd) { bd = s.x; bp = pbase + 2 * j; }
    if (s.y > bd) { bd = s.y; bp = pbase + 2 * j + 1; }
  }
  if (tid == 0) idx_lds[0] = 0;

  for (int i = 1; i < NPq; i++) {
    // wave max (value only) via DPP; full max lands in lane 63
    float wv = bd;
    wv = dpp_maxf<0x111, 0xf, 0xf>(wv);
    wv = dpp_maxf<0x112, 0xf, 0xf>(wv);
    wv = dpp_maxf<0x114, 0xf, 0xf>(wv);
    wv = dpp_maxf<0x118, 0xf, 0xf>(wv);
    wv = dpp_maxf<0x142, 0xa, 0xf>(wv);
    wv = dpp_maxf<0x143, 0xc, 0xf>(wv);
    float wmax = __int_as_float(__builtin_amdgcn_readlane(__float_as_int(wv), 63));
    unsigned long long msk = __ballot(bd == wmax);
    int wl = (int)__ffsll(msk) - 1;  // lowest tied lane = smallest index
    int wbp = __shfl(bp, wl);
    if (lane == 0) { sv[i & 1][wid] = wmax; spi[i & 1][wid] = wbp; }
    __syncthreads();

    // all threads scan the 8 wave slots; strict > keeps earliest wave on ties
    float bv = sv[i & 1][0];
    int bip = spi[i & 1][0];
#pragma unroll
    for (int w = 1; w < 8; w++) {
      float tv = sv[i & 1][w];
      bool t = tv > bv;
      bv = t ? tv : bv;
      bip = t ? spi[i & 1][w] : bip;
    }
    if (tid == 0) idx_lds[i] = bip;  // LDS, not global: no vmcnt store drain

    // winner coords from global (same addr per wave -> 1 request, L1/L2 hit)
    const float* cp = P + 3u * (unsigned int)bip;
    float cx = cp[0], cy = cp[1], cz = cp[2];

    // fused min-update + local argmax for next round
    bd = -1.0f;
    bp = pbase;
#pragma unroll
    for (int j = 0; j < 8; j++) {
      v2f s = dist2_v2(px[j], py[j], pz[j], cx, cy, cz);
      v2f nd;
      nd.x = fminf(dd[j].x, s.x);
      nd.y = fminf(dd[j].y, s.y);
      dd[j] = nd;
      if (nd.x > bd) { bd = nd.x; bp = pbase + 2 * j; }
      if (nd.y > bd) { bd = nd.y; bp = pbase + 2 * j + 1; }
    }
  }
  __syncthreads();
  // bulk coalesced dump of all 2048 indices
#pragma unroll
  for (int t = 0; t < NPq / 512; t++) {
    int g = t * 512 + tid;
    fps_idx[b * NPq + g] = idx_lds[g];
  }
}

// ---------------- K1b: gather sampled coords + sum-of-squares (+SoA copies) ----------------
__global__ __launch_bounds__(256) void k_gatherq(const float* __restrict__ pts,
                                                 const float* __restrict__ sump,
                                                 const int* __restrict__ fps_idx,
                                                 float* __restrict__ xyzq,
                                                 float* __restrict__ sumq,
                                                 float* __restrict__ xqs,
                                                 float* __restrict__ yqs,
                                                 float* __restrict__ zqs) {
  int g = blockIdx.x * 256 + threadIdx.x;  // over B*NP
  int b = g >> 11;
  int idx = fps_idx[g];
  int src = b * Nq + idx;
  float x = pts[src * 3 + 0], y = pts[src * 3 + 1], z = pts[src * 3 + 2];
  xyzq[g * 3 + 0] = x;
  xyzq[g * 3 + 1] = y;
  xyzq[g * 3 + 2] = z;
  xqs[g] = x; yqs[g] = y; zqs[g] = z;
  sumq[g] = sump[src];  // bitwise-identical to ref's sum(xyz_q**2)
}

// ---------------- K2: kNN top-17 per query + grouped mean-pool ----------------
// one block (256 thr) per query. Per-thread min key cached in a register; per
// round only the removed point's owner rescans its 32 entries. 1 barrier/round.
// Staging reads the packed (x,y,z,sump) float4 array: 1 dwordx4/point.
__global__ __launch_bounds__(256) void k_knn_group(const float4* __restrict__ pxyzs,
                                                   const float* __restrict__ xyzq,
                                                   const float* __restrict__ sumq,
                                                   const float* __restrict__ feats,
                                                   float* __restrict__ coarse_t) {
  const int blk = blockIdx.x;  // over B*NP
  const int b = blk >> 11;
  const int tid = threadIdx.x;
  const int lane = tid & 63, wid = tid >> 6;
  const float4* PS = pxyzs + (size_t)b * Nq;

  __shared__ float sq_lds[Nq];
  __shared__ unsigned long long wk[2][4];
  __shared__ int sel[KSEL];

  float qx = xyzq[blk * 3 + 0], qy = xyzq[blk * 3 + 1], qz = xyzq[blk * 3 + 2];
  float sq_ = sumq[blk];

  unsigned long long lmin = ~0ull;
#pragma unroll
  for (int k = 0; k < 32; k++) {
    int p = k * 256 + tid;
    float4 t = PS[p];
    float v = sq_expand(qx, qy, qz, sq_, t.x, t.y, t.z, t.w);
    sq_lds[p] = v;
    unsigned long long key = ((unsigned long long)__float_as_uint(v) << 32) | (unsigned int)p;
    lmin = key < lmin ? key : lmin;
  }
  // no barrier: each thread only ever touches its own sq_lds entries (p%256==tid)

  for (int r = 0; r < KSEL; r++) {
    unsigned long long key = lmin;
#pragma unroll
    for (int off = 32; off > 0; off >>= 1) {
      unsigned long long o = __shfl_down(key, off);
      key = o < key ? o : key;
    }
    if (lane == 0) wk[r & 1][wid] = key;
    __syncthreads();
    unsigned long long m = wk[r & 1][0];
    m = wk[r & 1][1] < m ? wk[r & 1][1] : m;
    m = wk[r & 1][2] < m ? wk[r & 1][2] : m;
    m = wk[r & 1][3] < m ? wk[r & 1][3] : m;
    int p = (int)(unsigned int)(m & 0xFFFFFFFFull);
    if (tid == 0) sel[r] = p;
    if ((p & 255) == tid) {  // owner removes winner and rebuilds its local min
      sq_lds[p] = __uint_as_float(0x7f800000u);
      lmin = ~0ull;
#pragma unroll
      for (int k = 0; k < 32; k++) {
        int pp = k * 256 + tid;
        unsigned long long kk =
            ((unsigned long long)__float_as_uint(sq_lds[pp]) << 32) | (unsigned int)pp;
        lmin = kk < lmin ? kk : lmin;
      }
    }
  }
  __syncthreads();

  // grouped mean over neighbors sel[1..16] (self at sel[0] dropped)
  if (tid < Cq) {
    const float* F = feats + ((size_t)(b * Cq + tid)) * Nq;
    float acc = 0.0f;
#pragma unroll
    for (int j = 1; j < KSEL; j++) acc += F[sel[j]];
    coarse_t[(size_t)blk * Cq + tid] = acc * (1.0f / 16.0f);
  }
}

// ---------------- K3: three_nn (top-3 queries per point) + weights ----------------
__device__ __forceinline__ void merge3(unsigned long long& a0, unsigned long long& a1,
                                       unsigned long long& a2, unsigned long long b0,
                                       unsigned long long b1, unsigned long long b2) {
  unsigned long long lo1 = a0 < b0 ? a0 : b0;
  unsigned long long hi1 = a0 < b0 ? b0 : a0;
  unsigned long long lo2 = a1 < b1 ? a1 : b1;
  unsigned long long hi2 = a1 < b1 ? b1 : a1;
  unsigned long long lo3 = a2 < b2 ? a2 : b2;
  unsigned long long c1 = hi1 < lo2 ? hi1 : lo2;
  unsigned long long m1 = hi1 < lo2 ? lo2 : hi1;
  unsigned long long m2 = hi2 < lo3 ? hi2 : lo3;
  a0 = lo1;
  a1 = c1;
  a2 = m1 < m2 ? m1 : m2;
}

__global__ __launch_bounds__(256) void k_three(const float* __restrict__ pts,
                                               const float* __restrict__ sump,
                                               const float* __restrict__ xqs,
                                               const float* __restrict__ yqs,
                                               const float* __restrict__ zqs,
                                               const float* __restrict__ sumq,
                                               int* __restrict__ i0, int* __restrict__ i1,
                                               int* __restrict__ i2, float* __restrict__ w0,
                                               float* __restrict__ w1, float* __restrict__ w2) {
  const int wid = threadIdx.x >> 6, lane = threadIdx.x & 63;
  const int n = blockIdx.x * 4 + wid;  // global over B*N
  const int b = n >> 13;
  float px = pts[n * 3 + 0], py = pts[n * 3 + 1], pz = pts[n * 3 + 2];
  float sp = sump[n];
  const float* QX = xqs + (size_t)b * NPq;
  const float* QY = yqs + (size_t)b * NPq;
  const float* QZ = zqs + (size_t)b * NPq;
  const float* SQ = sumq + (size_t)b * NPq;

  unsigned long long k0 = ~0ull, k1 = ~0ull, k2 = ~0ull;
#pragma unroll 4
  for (int j = 0; j < 32; j++) {
    int q = lane + j * 64;
    float v = sq_expand(QX[q], QY[q], QZ[q], SQ[q], px, py, pz, sp);
    unsigned long long key = ((unsigned long long)__float_as_uint(v) << 32) | (unsigned int)q;
    if (key < k2) {
      if (key < k1) {
        k2 = k1;
        if (key < k0) { k1 = k0; k0 = key; } else { k1 = key; }
      } else {
        k2 = key;
      }
    }
  }
#pragma unroll
  for (int off = 32; off > 0; off >>= 1) {
    unsigned long long o0 = __shfl_down(k0, off);
    unsigned long long o1 = __shfl_down(k1, off);
    unsigned long long o2 = __shfl_down(k2, off);
    merge3(k0, k1, k2, o0, o1, o2);
  }
  if (lane == 0) {
    float v0 = __uint_as_float((unsigned int)(k0 >> 32));
    float v1 = __uint_as_float((unsigned int)(k1 >> 32));
    float v2 = __uint_as_float((unsigned int)(k2 >> 32));
    float d0 = fmaxf(v0, 1e-10f), d1 = fmaxf(v1, 1e-10f), d2 = fmaxf(v2, 1e-10f);
    float inv0 = 1.0f / (d0 + 1e-8f);
    float inv1 = 1.0f / (d1 + 1e-8f);
    float inv2 = 1.0f / (d2 + 1e-8f);
    float s = inv0 + inv1 + inv2;
    i0[n] = (int)(unsigned int)(k0 & 0xFFFFFFFFull);
    i1[n] = (int)(unsigned int)(k1 & 0xFFFFFFFFull);
    i2[n] = (int)(unsigned int)(k2 & 0xFFFFFFFFull);
    w0[n] = inv0 / s;
    w1[n] = inv1 / s;
    w2[n] = inv2 / s;
  }
}

// ---------------- K4: inverse-distance interpolation ----------------
__global__ __launch_bounds__(256) void k_interp(const float* __restrict__ coarse_t,
                                                const int* __restrict__ i0,
                                                const int* __restrict__ i1,
                                                const int* __restrict__ i2,
                                                const float* __restrict__ w0,
                                                const float* __restrict__ w1,
                                                const float* __restrict__ w2,
                                                float* __restrict__ out) {
  int g = blockIdx.x * 256 + threadIdx.x;  // over B*N
  int b = g >> 13, n = g & (Nq - 1);
  int a0 = i0[g], a1 = i1[g], a2 = i2[g];
  float u0 = w0[g], u1 = w1[g], u2 = w2[g];
  const float4* r0 = (const float4*)(coarse_t + ((size_t)b * NPq + a0) * Cq);
  const float4* r1 = (const float4*)(coarse_t + ((size_t)b * NPq + a1) * Cq);
  const float4* r2 = (const float4*)(coarse_t + ((size_t)b * NPq + a2) * Cq);
  float* O = out + (size_t)b * Cq * Nq + n;
#pragma unroll 4
  for (int cq = 0; cq < Cq / 4; cq++) {
    float4 f0 = r0[cq], f1 = r1[cq], f2 = r2[cq];
    float o0 = u0 * f0.x + u1 * f1.x + u2 * f2.x;
    float o1 = u0 * f0.y + u1 * f1.y + u2 * f2.y;
    float o2 = u0 * f0.z + u1 * f1.z + u2 * f2.z;
    float o3 = u0 * f0.w + u1 * f1.w + u2 * f2.w;
    O[(size_t)(cq * 4 + 0) * Nq] = o0;
    O[(size_t)(cq * 4 + 1) * Nq] = o1;
    O[(size_t)(cq * 4 + 2) * Nq] = o2;
    O[(size_t)(cq * 4 + 3) * Nq] = o3;
  }
}

// ---------------- launch ----------------
extern "C" void kernel_launch(void* const* d_in, const int* in_sizes, int n_in,
                              void* d_out, int out_size, void* d_ws, size_t ws_size,
                              hipStream_t stream) {
  const float* pts = (const float*)d_in[0];    // [B,N,3]
  const float* feats = (const float*)d_in[1];  // [B,C,N]
  float* out = (float*)d_out;                  // [B,C,N]

  char* ws = (char*)d_ws;
  size_t off = 0;
  auto alloc = [&](size_t bytes) {
    void* p = ws + off;
    off += (bytes + 255) & ~(size_t)255;
    return p;
  };
  float* sump = (float*)alloc((size_t)Bq * Nq * 4);
  float4* pxyzs = (float4*)alloc((size_t)Bq * Nq * 16);
  int* fps_idx = (int*)alloc((size_t)Bq * NPq * 4);
  float* xyzq = (float*)alloc((size_t)Bq * NPq * 3 * 4);
  float* sumq = (float*)alloc((size_t)Bq * NPq * 4);
  float* coarse_t = (float*)alloc((size_t)Bq * NPq * Cq * 4);
  int* i0 = (int*)alloc((size_t)Bq * Nq * 4);
  int* i1 = (int*)alloc((size_t)Bq * Nq * 4);
  int* i2 = (int*)alloc((size_t)Bq * Nq * 4);
  float* w0 = (float*)alloc((size_t)Bq * Nq * 4);
  float* w1 = (float*)alloc((size_t)Bq * Nq * 4);
  float* w2 = (float*)alloc((size_t)Bq * Nq * 4);
  float* xqs = (float*)alloc((size_t)Bq * NPq * 4);
  float* yqs = (float*)alloc((size_t)Bq * NPq * 4);
  float* zqs = (float*)alloc((size_t)Bq * NPq * 4);

  k_sump<<<(Bq * Nq) / 256, 256, 0, stream>>>(pts, sump, pxyzs);
  k_fps<<<Bq, 512, 0, stream>>>(pts, fps_idx);
  k_gatherq<<<(Bq * NPq) / 256, 256, 0, stream>>>(pts, sump, fps_idx, xyzq, sumq, xqs, yqs, zqs);
  k_knn_group<<<Bq * NPq, 256, 0, stream>>>(pxyzs, xyzq, sumq, feats, coarse_t);
  k_three<<<(Bq * Nq) / 4, 256, 0, stream>>>(pts, sump, xqs, yqs, zqs, sumq, i0, i1, i2, w0, w1, w2);
  k_interp<<<(Bq * Nq) / 256, 256, 0, stream>>>(coarse_t, i0, i1, i2, w0, w1, w2, out);
}